// Round 3
// baseline (837.613 us; speedup 1.0000x reference)
//
#include <hip/hip_runtime.h>
#include <stdint.h>

typedef __attribute__((ext_vector_type(4))) float f32x4;
typedef __attribute__((ext_vector_type(8))) short bf16x8;

#define MFMA16(A, B, C) __builtin_amdgcn_mfma_f32_16x16x32_bf16(A, B, C, 0, 0, 0)

static __device__ __forceinline__ uint32_t f2bf_rne(float x) {
    uint32_t u = __builtin_bit_cast(uint32_t, x);
    return (u + 0x7FFFu + ((u >> 16) & 1u)) >> 16;   // RNE to bf16 bits
}
static __device__ __forceinline__ float bf2f(uint32_t b) {
    return __builtin_bit_cast(float, b << 16);
}
static __device__ __forceinline__ int fdswz(int d) { return (d & 7) ^ ((d >> 3) & 7); }

// RNE hi + RNE residual lo: x = hi + lo + O(2^-17 |x|)
static __device__ __forceinline__ void split_hl(float x, uint32_t& h, uint32_t& l) {
    h = f2bf_rne(x);
    l = f2bf_rne(x - bf2f(h));
}

// Causal attention, fp32 in/out, no scale, out layout [b][s][h*d].
// Correctness-hardened round: RNE hi/lo everywhere, 4-term QK^T, hi/lo P.
// One block = 4 waves = 64 q rows (16 per wave). KV tiles of 64.
__launch_bounds__(256, 2)
__global__ void fattn_kernel(const float* __restrict__ Q,
                             const float* __restrict__ K,
                             const float* __restrict__ V,
                             float* __restrict__ Out)
{
    constexpr int S = 4096, Dd = 128, KSTR = 136, PSTR = 72;
    __shared__ __align__(16) ushort lds_khi[64 * KSTR];   // K hi, [k][d], +8 pad (2-way free)
    __shared__ __align__(16) ushort lds_klo[64 * KSTR];   // K lo
    __shared__ __align__(16) ushort lds_vt [128 * 64];    // V^T [d][k], chunk-XOR swizzled
    __shared__ __align__(16) ushort lds_p  [4][16 * PSTR];// per-wave P, reused hi then lo

    const int tid = threadIdx.x;
    const int l   = tid & 63;
    const int w   = tid >> 6;
    const int lg  = l >> 4;        // lane group 0..3
    const int lc  = l & 15;        // lane col   0..15

    const int bid = blockIdx.x;
    const int qt  = 63 - (bid >> 5);      // heavy q-tiles first (causal skew)
    const int bh  = bid & 31;
    const int qb  = qt << 6;

    const size_t base = (size_t)bh * (S * Dd);
    const float* Qg = Q + base;
    const float* Kg = K + base;
    const float* Vg = V + base;

    // ---- Q fragments (hi/lo RNE), held in registers for the whole block ----
    const int qw   = qb + (w << 4);
    const int qrow = qw + lc;             // this lane's q (score layout: col)
    bf16x8 qhi[4], qlo[4];
#pragma unroll
    for (int t = 0; t < 4; ++t) {
        const float* src = Qg + (size_t)qrow * Dd + t * 32 + lg * 8;
        float xs[8];
        *(f32x4*)&xs[0] = *(const f32x4*)src;
        *(f32x4*)&xs[4] = *(const f32x4*)(src + 4);
        ushort hh[8], ll[8];
#pragma unroll
        for (int j = 0; j < 8; ++j) {
            uint32_t h, lo;
            split_hl(xs[j], h, lo);
            hh[j] = (ushort)h;
            ll[j] = (ushort)lo;
        }
        qhi[t] = *(bf16x8*)hh;
        qlo[t] = *(bf16x8*)ll;
    }

    float m_run = -INFINITY, l_run = 0.f;
    f32x4 Oacc[8];
#pragma unroll
    for (int dt = 0; dt < 8; ++dt) Oacc[dt] = (f32x4){0.f, 0.f, 0.f, 0.f};

    for (int kbase = 0; kbase <= qb; kbase += 64) {
        // ---- stage K tile (hi/lo RNE), coalesced, 8 float4 per thread ----
#pragma unroll
        for (int i = 0; i < 8; ++i) {
            int f  = i * 256 + tid;
            int kr = f >> 5;
            int d4 = (f & 31) << 2;
            f32x4 v = *(const f32x4*)(Kg + (size_t)(kbase + kr) * Dd + d4);
            uint32_t h[4], lo[4];
#pragma unroll
            for (int c = 0; c < 4; ++c) split_hl(v[c], h[c], lo[c]);
            int off = kr * KSTR + d4;
            *(uint2*)&lds_khi[off] = make_uint2(h[0] | (h[1] << 16), h[2] | (h[3] << 16));
            *(uint2*)&lds_klo[off] = make_uint2(lo[0] | (lo[1] << 16), lo[2] | (lo[3] << 16));
        }
        // ---- stage V^T (bf16 RNE): 4x4 register transpose, chunk-XOR swizzle ----
#pragma unroll
        for (int pass = 0; pass < 2; ++pass) {
            int k0 = ((tid >> 5) << 2) + (pass << 5);
            int d0 = (tid & 31) << 2;
            const float* vsrc = Vg + (size_t)(kbase + k0) * Dd + d0;
            f32x4 r0 = *(const f32x4*)(vsrc);
            f32x4 r1 = *(const f32x4*)(vsrc + Dd);
            f32x4 r2 = *(const f32x4*)(vsrc + 2 * Dd);
            f32x4 r3 = *(const f32x4*)(vsrc + 3 * Dd);
#pragma unroll
            for (int c = 0; c < 4; ++c) {
                int d = d0 + c;
                int chunk = (k0 >> 3) ^ fdswz(d);
                int off = d * 64 + (chunk << 3) + (k0 & 7);
                *(uint2*)&lds_vt[off] = make_uint2(f2bf_rne(r0[c]) | (f2bf_rne(r1[c]) << 16),
                                                   f2bf_rne(r2[c]) | (f2bf_rne(r3[c]) << 16));
            }
        }
        __syncthreads();

        // ---- S^T = K·Q^T, exact 4-term hi/lo (4 MFMAs per 32-d step) ----
        f32x4 sv[4];
#pragma unroll
        for (int s = 0; s < 4; ++s) {
            f32x4 accA = (f32x4){0.f, 0.f, 0.f, 0.f};
            f32x4 accB = (f32x4){0.f, 0.f, 0.f, 0.f};
            const int krow = (s << 4) + lc;
#pragma unroll
            for (int tt = 0; tt < 4; ++tt) {
                int off = krow * KSTR + tt * 32 + lg * 8;
                bf16x8 ka = *(const bf16x8*)&lds_khi[off];
                bf16x8 kl = *(const bf16x8*)&lds_klo[off];
                accA = MFMA16(ka, qhi[tt], accA);   // khi*qhi
                accB = MFMA16(ka, qlo[tt], accB);   // khi*qlo
                accA = MFMA16(kl, qhi[tt], accA);   // klo*qhi
                accB = MFMA16(kl, qlo[tt], accB);   // klo*qlo
            }
            sv[s] = accA + accB;
        }

        // ---- causal mask + online softmax (state per q = lane col lc) ----
        float mloc = -INFINITY;
#pragma unroll
        for (int s = 0; s < 4; ++s) {
            int kg0 = kbase + (s << 4) + (lg << 2);
#pragma unroll
            for (int r = 0; r < 4; ++r) {
                float val = (kg0 + r > qrow) ? -1e30f : sv[s][r];
                sv[s][r] = val;
                mloc = fmaxf(mloc, val);
            }
        }
        mloc = fmaxf(mloc, __shfl_xor(mloc, 16));
        mloc = fmaxf(mloc, __shfl_xor(mloc, 32));
        float m_new = fmaxf(m_run, mloc);
        float scale = __expf(m_run - m_new);   // first tile: exp(-inf)=0, no NaN

        float lsum = 0.f;
#pragma unroll
        for (int s = 0; s < 4; ++s)
#pragma unroll
            for (int r = 0; r < 4; ++r) {
                float p = __expf(sv[s][r] - m_new);
                sv[s][r] = p;
                lsum += p;
            }
        lsum += __shfl_xor(lsum, 16);
        lsum += __shfl_xor(lsum, 32);
        l_run = l_run * scale + lsum;
        m_run = m_new;

        // rescale O (O rows are q = 4*lg + r; per-row scale via shuffle)
        float sc[4];
#pragma unroll
        for (int r = 0; r < 4; ++r)
            sc[r] = __shfl(scale, (l & 48) | (lg << 2) | r);
#pragma unroll
        for (int dt = 0; dt < 8; ++dt)
#pragma unroll
            for (int r = 0; r < 4; ++r) Oacc[dt][r] *= sc[r];

        // ---- P hi -> wave-private LDS, read hi-fragments ----
#pragma unroll
        for (int s = 0; s < 4; ++s) {
            uint32_t p0 = f2bf_rne(sv[s][0]) | (f2bf_rne(sv[s][1]) << 16);
            uint32_t p1 = f2bf_rne(sv[s][2]) | (f2bf_rne(sv[s][3]) << 16);
            int off = lc * PSTR + (s << 4) + (lg << 2);
            *(uint2*)&lds_p[w][off] = make_uint2(p0, p1);
        }
        asm volatile("s_waitcnt lgkmcnt(0)" ::: "memory");
        __builtin_amdgcn_sched_barrier(0);
        bf16x8 ph[2];
#pragma unroll
        for (int ks = 0; ks < 2; ++ks)
            ph[ks] = *(const bf16x8*)&lds_p[w][lc * PSTR + (ks << 5) + (lg << 3)];
        asm volatile("s_waitcnt lgkmcnt(0)" ::: "memory");   // reads done before overwrite
        __builtin_amdgcn_sched_barrier(0);

        // ---- P lo -> same LDS, read lo-fragments ----
#pragma unroll
        for (int s = 0; s < 4; ++s) {
            uint32_t lo4[4];
#pragma unroll
            for (int r = 0; r < 4; ++r) {
                uint32_t hb = f2bf_rne(sv[s][r]);
                lo4[r] = f2bf_rne(sv[s][r] - bf2f(hb));
            }
            int off = lc * PSTR + (s << 4) + (lg << 2);
            *(uint2*)&lds_p[w][off] = make_uint2(lo4[0] | (lo4[1] << 16), lo4[2] | (lo4[3] << 16));
        }
        asm volatile("s_waitcnt lgkmcnt(0)" ::: "memory");
        __builtin_amdgcn_sched_barrier(0);
        bf16x8 pl[2];
#pragma unroll
        for (int ks = 0; ks < 2; ++ks)
            pl[ks] = *(const bf16x8*)&lds_p[w][lc * PSTR + (ks << 5) + (lg << 3)];
        asm volatile("s_waitcnt lgkmcnt(0)" ::: "memory");
        __builtin_amdgcn_sched_barrier(0);

        // ---- PV: O[q][d] += (Phi+Plo)[q][k] * V[k][d] ----
#pragma unroll
        for (int ks = 0; ks < 2; ++ks) {
#pragma unroll
            for (int dt = 0; dt < 8; ++dt) {
                int d = (dt << 4) + lc;
                int chunk = ((ks << 2) + lg) ^ fdswz(d);
                bf16x8 vf = *(const bf16x8*)&lds_vt[d * 64 + (chunk << 3)];
                Oacc[dt] = MFMA16(ph[ks], vf, Oacc[dt]);
                Oacc[dt] = MFMA16(pl[ks], vf, Oacc[dt]);
            }
        }
        __syncthreads();
    }

    // ---- epilogue: normalize by l, store [b][q][h][d] fp32 ----
    float linv[4];
#pragma unroll
    for (int r = 0; r < 4; ++r)
        linv[r] = 1.0f / __shfl(l_run, (l & 48) | (lg << 2) | r);

    const int b_ = bh >> 4, h_ = bh & 15;
#pragma unroll
    for (int r = 0; r < 4; ++r) {
        size_t orow = ((size_t)b_ * S + (qw + (lg << 2) + r)) * 2048 + h_ * 128;
#pragma unroll
        for (int dt = 0; dt < 8; ++dt)
            Out[orow + (dt << 4) + lc] = Oacc[dt][r] * linv[r];
    }
}

extern "C" void kernel_launch(void* const* d_in, const int* in_sizes, int n_in,
                              void* d_out, int out_size, void* d_ws, size_t ws_size,
                              hipStream_t stream) {
    const float* Q = (const float*)d_in[0];
    const float* K = (const float*)d_in[1];
    const float* V = (const float*)d_in[2];
    float* Out = (float*)d_out;
    // attention_mask (d_in[3]) is the causal mask by construction; applied analytically.
    fattn_kernel<<<dim3(2048), dim3(256), 0, stream>>>(Q, K, V, Out);
}